// Round 4
// baseline (584.716 us; speedup 1.0000x reference)
//
#include <hip/hip_runtime.h>

// ---------------------------------------------------------------------------
// TraceSemanticHandshakeV342: fused concat+LayerNorm+Linear+GELU+Linear+GELU
// b=4, m=256, h=64, d=256, CAT=1283.  Rows = b*m*h = 65536.
// One block per (b,m): M=64, N=256, K=1280 bf16 MFMA GEMM, LN in epilogue.
// Structure = round-2 (verified 211us, 128 VGPR, no spill).  THIS REVISION:
// LDS diet 67KB -> 34KB so 4 blocks/CU fit (16 waves/CU, whole grid
// co-resident): pst stat-scratch ALIASES the As tile (barrier after GEMM1),
// y1 stored as bf16 in the same 32KB (round-0 scatter-write idiom).
// __launch_bounds__(256,4) keeps the 128-VGPR cap round 2 already achieved.
// (Round-3 8-wave experiment: compiler went to 64 VGPR and spilled 450MB to
// scratch -- reverted.)
// ---------------------------------------------------------------------------

typedef float  f32x4 __attribute__((ext_vector_type(4)));
typedef short  s16x8 __attribute__((ext_vector_type(8)));

__device__ __forceinline__ unsigned short f2bf(float f) {
    unsigned u = __builtin_bit_cast(unsigned, f);
    return (unsigned short)((u + 0x7fffu + ((u >> 16) & 1u)) >> 16);
}
__device__ __forceinline__ unsigned f2bf_pk(float lo, float hi) {
    unsigned ulo = __builtin_bit_cast(unsigned, lo);
    unsigned uhi = __builtin_bit_cast(unsigned, hi);
    ulo = (ulo + 0x7fffu + ((ulo >> 16) & 1u)) >> 16;
    uhi = (uhi + 0x7fffu + ((uhi >> 16) & 1u)) & 0xffff0000u;
    return ulo | uhi;
}
// tanh-form GELU: x*sigmoid(2*0.79788456*(x+0.044715 x^3)); max err ~4e-4.
__device__ __forceinline__ float gelu_t(float x) {
    float u2 = 1.5957691216057308f * x + 0.07135481627f * (x * x * x);
    float e  = __expf(u2);
    float r  = __builtin_amdgcn_rcpf(e + 1.0f);   // 1/(1+e^{2u}) ; e=inf -> 0
    return x - x * r;                              // x*sigmoid(2u)
}

// ---------------------------------------------------------------------------
// Prep: builds in d_ws (no memset / atomics)
//   w1L bf16 K-blocked: w1L[(kb*256+n)*32+kl] = gamma[k]*W1[k][n], kb<40
//   w2L bf16 K-blocked: w2L[(kb*256+n)*32+kl] = W2[k][n],          kb<8
//   Sg[256], Sb[256] f32: block 48 computes full column sums directly.
// ---------------------------------------------------------------------------
__global__ void __launch_bounds__(256)
prep_k(const float* __restrict__ W1, const float* __restrict__ W2,
       const float* __restrict__ gamma, const float* __restrict__ beta,
       float* __restrict__ Sg, float* __restrict__ Sb,
       short* __restrict__ w1t, short* __restrict__ w2t)
{
    __shared__ float tile[32][257];
    const int blk = blockIdx.x;
    const int t   = threadIdx.x;
    const int nl  = t >> 2, c = t & 3;    // per-wave: contiguous 1KB stores
    if (blk < 40) {
#pragma unroll 4
        for (int kl = 0; kl < 32; ++kl) {
            int k = blk * 32 + kl;
            tile[kl][t] = gamma[k] * W1[k * 256 + t];   // coalesced 1KB row
        }
        __syncthreads();
#pragma unroll
        for (int gi = 0; gi < 4; ++gi) {
            int n = gi * 64 + nl;
            uint4 o;
            o.x = f2bf_pk(tile[c*8+0][n], tile[c*8+1][n]);
            o.y = f2bf_pk(tile[c*8+2][n], tile[c*8+3][n]);
            o.z = f2bf_pk(tile[c*8+4][n], tile[c*8+5][n]);
            o.w = f2bf_pk(tile[c*8+6][n], tile[c*8+7][n]);
            *(uint4*)(w1t + (blk * 256 + n) * 32 + c * 8) = o;
        }
    } else if (blk < 48) {
        const int kb = blk - 40;
#pragma unroll 4
        for (int kl = 0; kl < 32; ++kl) {
            int k = kb * 32 + kl;
            tile[kl][t] = W2[k * 256 + t];
        }
        __syncthreads();
#pragma unroll
        for (int gi = 0; gi < 4; ++gi) {
            int n = gi * 64 + nl;
            uint4 o;
            o.x = f2bf_pk(tile[c*8+0][n], tile[c*8+1][n]);
            o.y = f2bf_pk(tile[c*8+2][n], tile[c*8+3][n]);
            o.z = f2bf_pk(tile[c*8+4][n], tile[c*8+5][n]);
            o.w = f2bf_pk(tile[c*8+6][n], tile[c*8+7][n]);
            *(uint4*)(w2t + (kb * 256 + n) * 32 + c * 8) = o;
        }
    } else {
        // full column sums Sg/Sb (replaces memset+atomics)
        const int n = t;
        float sg = 0.f, sb = 0.f;
#pragma unroll 8
        for (int k = 0; k < 1280; ++k) {
            float w = W1[k * 256 + n];
            sg += gamma[k] * w;
            sb += beta[k]  * w;
        }
        Sg[n] = sg;
        Sb[n] = sb;
    }
}

// ---------------------------------------------------------------------------
// Main fused kernel. grid = 1024 (one per (b,m)); block = 256 (4 waves).
// Wave w: GEMM columns [w*64, w*64+64); staging rows [w*16, w*16+16).
// LDS (34048 B -> 4 blocks/CU, whole grid co-resident):
//   [0,32KB):  As bf16 A-tile [64 rows][32 x 16B chunks, XOR-swz]   (GEMM1)
//              pst f32 [2][64][64] stat partials (aliases As, after GEMM1)
//              y16 bf16 [64][256] y1 tile (aliases, after stats)    (GEMM2)
//   [32KB,+1280): mu/rs/t0/t1/t2 [64] each
// ---------------------------------------------------------------------------
__global__ void __launch_bounds__(256, 4)
fused_main(const float* __restrict__ token, const float* __restrict__ step,
           const float* __restrict__ dyn,   const float* __restrict__ sem,
           const float* __restrict__ trace, const float* __restrict__ rel,
           const float* __restrict__ vis,   const float* __restrict__ gamma,
           const float* __restrict__ beta,  const float* __restrict__ W1,
           const float* __restrict__ b1v,   const float* __restrict__ b2v,
           const float* __restrict__ Sg,    const float* __restrict__ Sb,
           const short* __restrict__ w1t,   const short* __restrict__ w2t,
           float* __restrict__ out)
{
    __shared__ __align__(16) char lds_raw[34048];
    uint4* As                 = (uint4*)lds_raw;                 // 32 KB
    unsigned long long* As8   = (unsigned long long*)lds_raw;
    float* pst                = (float*)lds_raw;                 // aliases As
    unsigned short* y16       = (unsigned short*)lds_raw;        // aliases As
    float* mu_s               = (float*)(lds_raw + 32768);
    float* rs_s               = mu_s + 64;
    float* t0s                = mu_s + 128;
    float* t1s                = mu_s + 192;
    float* t2s                = mu_s + 256;

    const int t    = threadIdx.x;
    const int bm   = blockIdx.x;          // b*256 + m
    const int b_i  = bm >> 8;
    const int lane = t & 63;
    const int wv   = t >> 6;
    const int l15  = lane & 15;
    const int q    = lane >> 4;
    const int n0   = wv * 64;             // GEMM column base
    const int r0   = wv * 16;             // staging row base

    const float* base0 = token + bm * 256;                  // stride 0
    const float* base1 = step  + (b_i * 64 + r0) * 256;
    const float* base2 = dyn   + (bm * 64 + r0) * 256;
    const float* base3 = sem   + (bm * 64 + r0) * 256;
    const float* base4 = trace + (bm * 64 + r0) * 256;

    f32x4 acc[4][4];
    float s1[16], s2[16];
#pragma unroll
    for (int i = 0; i < 4; ++i)
#pragma unroll
        for (int j = 0; j < 4; ++j)
            acc[i][j] = (f32x4){0.f, 0.f, 0.f, 0.f};
#pragma unroll
    for (int j = 0; j < 16; ++j) { s1[j] = 0.f; s2[j] = 0.f; }

    float4 g[16];

    // Coalesced wave-per-row load: lane l reads bytes [l*16, l*16+16) of row j.
#define LOAD_SEG(BASE, STRIDE)                                                 \
    _Pragma("unroll")                                                          \
    for (int j = 0; j < 16; ++j)                                               \
        g[j] = *((const float4*)((BASE) + j * (STRIDE)) + lane);

    // Consume g: accumulate per-lane LN partials, pack to bf16, write As with
    // 16B-chunk XOR swizzle (chunk c = lane>>1, half = lane&1; c ^= row&7).
#define STATS_CVT_WRITE()                                                      \
    _Pragma("unroll")                                                          \
    for (int j = 0; j < 16; ++j) {                                             \
        float4 v = g[j];                                                       \
        s1[j] += v.x + v.y + v.z + v.w;                                        \
        s2[j] += v.x*v.x + v.y*v.y + v.z*v.z + v.w*v.w;                        \
        int m_ = r0 + j;                                                       \
        unsigned long long pk_ = (unsigned long long)f2bf_pk(v.x, v.y)         \
                               | ((unsigned long long)f2bf_pk(v.z, v.w) << 32);\
        As8[(m_ * 32 + ((lane >> 1) ^ (j & 7))) * 2 + (lane & 1)] = pk_;       \
    }

    // B loads coalesced: per (kc,nt) the wave reads a contiguous 1KB of
    // w1L[kb = SEG*8+kc][n0+nt*16 .. +16][0..32).
#define MFMA_SEG(SEG)                                                          \
    _Pragma("unroll")                                                          \
    for (int kc = 0; kc < 8; ++kc) {                                           \
        const short* wk_ = w1t + ((SEG) * 8 + kc) * 8192;                      \
        s16x8 bfr[4];                                                          \
        _Pragma("unroll")                                                      \
        for (int nt = 0; nt < 4; ++nt)                                         \
            bfr[nt] = *(const s16x8*)(wk_ + (n0 + nt * 16 + l15) * 32 + q * 8);\
        s16x8 afr[4];                                                          \
        _Pragma("unroll")                                                      \
        for (int mt = 0; mt < 4; ++mt) {                                       \
            int m_ = mt * 16 + l15;                                            \
            afr[mt] = *(const s16x8*)&As[m_ * 32 + ((kc * 4 + q) ^ (m_ & 7))]; \
        }                                                                      \
        _Pragma("unroll")                                                      \
        for (int mt = 0; mt < 4; ++mt)                                         \
            _Pragma("unroll")                                                  \
            for (int nt = 0; nt < 4; ++nt)                                     \
                acc[mt][nt] = __builtin_amdgcn_mfma_f32_16x16x32_bf16(         \
                    afr[mt], bfr[nt], acc[mt][nt], 0, 0, 0);                   \
    }

    // ---- software-pipelined GEMM1: load(s+1) issued before MFMA(s) --------
    LOAD_SEG(base0, 0);            // token broadcast (CSEs to one load)
    STATS_CVT_WRITE();
    __syncthreads();
    LOAD_SEG(base1, 256);
    MFMA_SEG(0);
    __syncthreads();
    STATS_CVT_WRITE();
    __syncthreads();
    LOAD_SEG(base2, 256);
    MFMA_SEG(1);
    __syncthreads();
    STATS_CVT_WRITE();
    __syncthreads();
    LOAD_SEG(base3, 256);
    MFMA_SEG(2);
    __syncthreads();
    STATS_CVT_WRITE();
    __syncthreads();
    LOAD_SEG(base4, 256);
    MFMA_SEG(3);
    __syncthreads();
    STATS_CVT_WRITE();
    __syncthreads();
    MFMA_SEG(4);
    __syncthreads();               // As reads done everywhere; pst may overlay

    // ---- LN stats: per-lane partials -> pst (aliases As) -> 1-wave reduce -
    // write: lane l, row r: f32 index ((l>>2)^(r&7))*4 + (l&3) within row.
#pragma unroll
    for (int j = 0; j < 16; ++j) {
        int r  = r0 + j;
        int ci = (((lane >> 2) ^ (j & 7)) << 2) + (lane & 3);
        pst[r * 64 + ci]        = s1[j];
        pst[4096 + r * 64 + ci] = s2[j];
    }
    __syncthreads();

    if (t < 64) {
        const int r = t;
        float S1 = 0.f, S2 = 0.f;
#pragma unroll
        for (int i = 0; i < 16; ++i) {
            int c = i ^ (r & 7);
            const f32x4 a = *(const f32x4*)&pst[r * 64 + (c << 2)];
            const f32x4 b = *(const f32x4*)&pst[4096 + r * 64 + (c << 2)];
            S1 += a[0] + a[1] + a[2] + a[3];
            S2 += b[0] + b[1] + b[2] + b[3];
        }
        float x0 = rel[(bm * 64 + r) * 2 + 0];
        float x1 = rel[(bm * 64 + r) * 2 + 1];
        float x2 = vis[bm * 64 + r];
        S1 += x0 + x1 + x2;
        S2 += x0 * x0 + x1 * x1 + x2 * x2;
        const float inv = 1.0f / 1283.0f;
        float mu  = S1 * inv;
        float var = S2 * inv - mu * mu;
        float rs  = rsqrtf(var + 1e-5f);
        mu_s[r] = mu;
        rs_s[r] = rs;
        t0s[r] = (x0 - mu) * rs * gamma[1280] + beta[1280];
        t1s[r] = (x1 - mu) * rs * gamma[1281] + beta[1281];
        t2s[r] = (x2 - mu) * rs * gamma[1282] + beta[1282];
    }
    __syncthreads();               // stats published; pst reads done

    // ---- epilogue 1: LN fixup + tail + bias + GELU -> y1 bf16 (overlays) --
#pragma unroll
    for (int nt = 0; nt < 4; ++nt) {
        int n = n0 + nt * 16 + l15;
        float sg  = Sg[n], sb = Sb[n], bb = b1v[n];
        float wt0 = W1[1280 * 256 + n];
        float wt1 = W1[1281 * 256 + n];
        float wt2 = W1[1282 * 256 + n];
#pragma unroll
        for (int mt = 0; mt < 4; ++mt) {
#pragma unroll
            for (int r4 = 0; r4 < 4; ++r4) {
                int r = mt * 16 + q * 4 + r4;
                float rsv = rs_s[r], muv = mu_s[r];
                float v = rsv * acc[mt][nt][r4] - rsv * muv * sg + sb + bb
                        + t0s[r] * wt0 + t1s[r] * wt1 + t2s[r] * wt2;
                v = gelu_t(v);
                int chunk = (n >> 3) ^ (r & 7);
                y16[(r * 32 + chunk) * 8 + (n & 7)] = f2bf(v);
            }
        }
    }
    __syncthreads();

    // ---- GEMM2: y1 (bf16 in LDS) @ w2L (coalesced global) -----------------
    f32x4 acc2[4][4];
#pragma unroll
    for (int i = 0; i < 4; ++i)
#pragma unroll
        for (int j = 0; j < 4; ++j)
            acc2[i][j] = (f32x4){0.f, 0.f, 0.f, 0.f};

#pragma unroll
    for (int kc = 0; kc < 8; ++kc) {
        const short* wk = w2t + kc * 8192;
        s16x8 bfr[4];
#pragma unroll
        for (int nt = 0; nt < 4; ++nt)
            bfr[nt] = *(const s16x8*)(wk + (n0 + nt * 16 + l15) * 32 + q * 8);
        s16x8 afr[4];
#pragma unroll
        for (int mt = 0; mt < 4; ++mt) {
            int m_ = mt * 16 + l15;
            afr[mt] = *(const s16x8*)&As[m_ * 32 + ((kc * 4 + q) ^ (m_ & 7))];
        }
#pragma unroll
        for (int mt = 0; mt < 4; ++mt)
#pragma unroll
            for (int nt = 0; nt < 4; ++nt)
                acc2[mt][nt] = __builtin_amdgcn_mfma_f32_16x16x32_bf16(
                    afr[mt], bfr[nt], acc2[mt][nt], 0, 0, 0);
    }

    // ---- epilogue 2: + b2, GELU, store f32 --------------------------------
#pragma unroll
    for (int nt = 0; nt < 4; ++nt) {
        int n = n0 + nt * 16 + l15;
        float bb = b2v[n];
#pragma unroll
        for (int mt = 0; mt < 4; ++mt)
#pragma unroll
            for (int r4 = 0; r4 < 4; ++r4) {
                int r = mt * 16 + q * 4 + r4;
                out[(bm * 64 + r) * 256 + n] = gelu_t(acc2[mt][nt][r4] + bb);
            }
    }
#undef LOAD_SEG
#undef STATS_CVT_WRITE
#undef MFMA_SEG
}

// ---------------------------------------------------------------------------
extern "C" void kernel_launch(void* const* d_in, const int* in_sizes, int n_in,
                              void* d_out, int out_size, void* d_ws, size_t ws_size,
                              hipStream_t stream) {
    const float* token = (const float*)d_in[0];
    const float* step  = (const float*)d_in[1];
    const float* dyn   = (const float*)d_in[2];
    const float* sem   = (const float*)d_in[3];
    const float* trace = (const float*)d_in[4];
    const float* rel   = (const float*)d_in[5];
    const float* vis   = (const float*)d_in[6];
    const float* gamma = (const float*)d_in[7];
    const float* beta  = (const float*)d_in[8];
    const float* W1    = (const float*)d_in[9];
    const float* b1    = (const float*)d_in[10];
    const float* W2    = (const float*)d_in[11];
    const float* b2    = (const float*)d_in[12];

    // ws layout: [0,1KB) Sg f32, [1KB,2KB) Sb f32, then w1L bf16 (655360 B),
    // then w2L bf16 (131072 B).  Total 788480 B.
    float* Sg  = (float*)d_ws;
    float* Sb  = Sg + 256;
    short* w1t = (short*)((char*)d_ws + 2048);
    short* w2t = w1t + 1280 * 256;
    float* out = (float*)d_out;

    hipLaunchKernelGGL(prep_k, dim3(49), dim3(256), 0, stream,
                       W1, W2, gamma, beta, Sg, Sb, w1t, w2t);
    hipLaunchKernelGGL(fused_main, dim3(1024), dim3(256), 0, stream,
                       token, step, dyn, sem, trace, rel, vis, gamma, beta,
                       W1, b1, b2, Sg, Sb, w1t, w2t, out);
}

// Round 5
// 357.908 us; speedup vs baseline: 1.6337x; 1.6337x over previous
//
#include <hip/hip_runtime.h>

// ---------------------------------------------------------------------------
// TraceSemanticHandshakeV342: fused concat+LayerNorm+Linear+GELU+Linear+GELU
// b=4, m=256, h=64, d=256, CAT=1283.  Rows = b*m*h = 65536.
// One block per (b,m): M=64, N=256, K=1280 bf16 MFMA GEMM, LN in epilogue.
// Structure = round-2 body (verified 211us @128 VGPR no-spill) + round-4 LDS
// diet (34KB -> 4 blocks/CU).  THIS REVISION changes ONE thing vs round 4:
// __launch_bounds__(256, 2).  Measured compiler rule: VGPR cap = 256/minwaves
//   (256,2) -> 128 VGPR, no spill (round 2: FETCH 110MB, WRITE 100MB)
//   (256,4) -> 64 VGPR, 850MB scratch spill (round 4: 380us)
// 128 VGPR = 4 waves/SIMD (512-reg file) and 34KB LDS = 4 blocks/CU, so both
// limits now land on 16 waves/CU together.
// ---------------------------------------------------------------------------

typedef float  f32x4 __attribute__((ext_vector_type(4)));
typedef short  s16x8 __attribute__((ext_vector_type(8)));

__device__ __forceinline__ unsigned short f2bf(float f) {
    unsigned u = __builtin_bit_cast(unsigned, f);
    return (unsigned short)((u + 0x7fffu + ((u >> 16) & 1u)) >> 16);
}
__device__ __forceinline__ unsigned f2bf_pk(float lo, float hi) {
    unsigned ulo = __builtin_bit_cast(unsigned, lo);
    unsigned uhi = __builtin_bit_cast(unsigned, hi);
    ulo = (ulo + 0x7fffu + ((ulo >> 16) & 1u)) >> 16;
    uhi = (uhi + 0x7fffu + ((uhi >> 16) & 1u)) & 0xffff0000u;
    return ulo | uhi;
}
// tanh-form GELU: x*sigmoid(2*0.79788456*(x+0.044715 x^3)); max err ~4e-4.
__device__ __forceinline__ float gelu_t(float x) {
    float u2 = 1.5957691216057308f * x + 0.07135481627f * (x * x * x);
    float e  = __expf(u2);
    float r  = __builtin_amdgcn_rcpf(e + 1.0f);   // 1/(1+e^{2u}) ; e=inf -> 0
    return x - x * r;                              // x*sigmoid(2u)
}

// ---------------------------------------------------------------------------
// Prep: builds in d_ws (no memset / atomics)
//   w1L bf16 K-blocked: w1L[(kb*256+n)*32+kl] = gamma[k]*W1[k][n], kb<40
//   w2L bf16 K-blocked: w2L[(kb*256+n)*32+kl] = W2[k][n],          kb<8
//   Sg[256], Sb[256] f32: block 48 computes full column sums directly.
// ---------------------------------------------------------------------------
__global__ void __launch_bounds__(256)
prep_k(const float* __restrict__ W1, const float* __restrict__ W2,
       const float* __restrict__ gamma, const float* __restrict__ beta,
       float* __restrict__ Sg, float* __restrict__ Sb,
       short* __restrict__ w1t, short* __restrict__ w2t)
{
    __shared__ float tile[32][257];
    const int blk = blockIdx.x;
    const int t   = threadIdx.x;
    const int nl  = t >> 2, c = t & 3;    // per-wave: contiguous 1KB stores
    if (blk < 40) {
#pragma unroll 4
        for (int kl = 0; kl < 32; ++kl) {
            int k = blk * 32 + kl;
            tile[kl][t] = gamma[k] * W1[k * 256 + t];   // coalesced 1KB row
        }
        __syncthreads();
#pragma unroll
        for (int gi = 0; gi < 4; ++gi) {
            int n = gi * 64 + nl;
            uint4 o;
            o.x = f2bf_pk(tile[c*8+0][n], tile[c*8+1][n]);
            o.y = f2bf_pk(tile[c*8+2][n], tile[c*8+3][n]);
            o.z = f2bf_pk(tile[c*8+4][n], tile[c*8+5][n]);
            o.w = f2bf_pk(tile[c*8+6][n], tile[c*8+7][n]);
            *(uint4*)(w1t + (blk * 256 + n) * 32 + c * 8) = o;
        }
    } else if (blk < 48) {
        const int kb = blk - 40;
#pragma unroll 4
        for (int kl = 0; kl < 32; ++kl) {
            int k = kb * 32 + kl;
            tile[kl][t] = W2[k * 256 + t];
        }
        __syncthreads();
#pragma unroll
        for (int gi = 0; gi < 4; ++gi) {
            int n = gi * 64 + nl;
            uint4 o;
            o.x = f2bf_pk(tile[c*8+0][n], tile[c*8+1][n]);
            o.y = f2bf_pk(tile[c*8+2][n], tile[c*8+3][n]);
            o.z = f2bf_pk(tile[c*8+4][n], tile[c*8+5][n]);
            o.w = f2bf_pk(tile[c*8+6][n], tile[c*8+7][n]);
            *(uint4*)(w2t + (kb * 256 + n) * 32 + c * 8) = o;
        }
    } else {
        // full column sums Sg/Sb (replaces memset+atomics)
        const int n = t;
        float sg = 0.f, sb = 0.f;
#pragma unroll 8
        for (int k = 0; k < 1280; ++k) {
            float w = W1[k * 256 + n];
            sg += gamma[k] * w;
            sb += beta[k]  * w;
        }
        Sg[n] = sg;
        Sb[n] = sb;
    }
}

// ---------------------------------------------------------------------------
// Main fused kernel. grid = 1024 (one per (b,m)); block = 256 (4 waves).
// Wave w: GEMM columns [w*64, w*64+64); staging rows [w*16, w*16+16).
// LDS (34048 B -> 4 blocks/CU):
//   [0,32KB):  As bf16 A-tile [64 rows][32 x 16B chunks, XOR-swz]   (GEMM1)
//              pst f32 [2][64][64] stat partials (aliases As, after GEMM1)
//              y16 bf16 [64][256] y1 tile (aliases, after stats)    (GEMM2)
//   [32KB,+1280): mu/rs/t0/t1/t2 [64] each
// ---------------------------------------------------------------------------
__global__ void __launch_bounds__(256, 2)
fused_main(const float* __restrict__ token, const float* __restrict__ step,
           const float* __restrict__ dyn,   const float* __restrict__ sem,
           const float* __restrict__ trace, const float* __restrict__ rel,
           const float* __restrict__ vis,   const float* __restrict__ gamma,
           const float* __restrict__ beta,  const float* __restrict__ W1,
           const float* __restrict__ b1v,   const float* __restrict__ b2v,
           const float* __restrict__ Sg,    const float* __restrict__ Sb,
           const short* __restrict__ w1t,   const short* __restrict__ w2t,
           float* __restrict__ out)
{
    __shared__ __align__(16) char lds_raw[34048];
    uint4* As                 = (uint4*)lds_raw;                 // 32 KB
    unsigned long long* As8   = (unsigned long long*)lds_raw;
    float* pst                = (float*)lds_raw;                 // aliases As
    unsigned short* y16       = (unsigned short*)lds_raw;        // aliases As
    float* mu_s               = (float*)(lds_raw + 32768);
    float* rs_s               = mu_s + 64;
    float* t0s                = mu_s + 128;
    float* t1s                = mu_s + 192;
    float* t2s                = mu_s + 256;

    const int t    = threadIdx.x;
    const int bm   = blockIdx.x;          // b*256 + m
    const int b_i  = bm >> 8;
    const int lane = t & 63;
    const int wv   = t >> 6;
    const int l15  = lane & 15;
    const int q    = lane >> 4;
    const int n0   = wv * 64;             // GEMM column base
    const int r0   = wv * 16;             // staging row base

    const float* base0 = token + bm * 256;                  // stride 0
    const float* base1 = step  + (b_i * 64 + r0) * 256;
    const float* base2 = dyn   + (bm * 64 + r0) * 256;
    const float* base3 = sem   + (bm * 64 + r0) * 256;
    const float* base4 = trace + (bm * 64 + r0) * 256;

    f32x4 acc[4][4];
    float s1[16], s2[16];
#pragma unroll
    for (int i = 0; i < 4; ++i)
#pragma unroll
        for (int j = 0; j < 4; ++j)
            acc[i][j] = (f32x4){0.f, 0.f, 0.f, 0.f};
#pragma unroll
    for (int j = 0; j < 16; ++j) { s1[j] = 0.f; s2[j] = 0.f; }

    float4 g[16];

    // Coalesced wave-per-row load: lane l reads bytes [l*16, l*16+16) of row j.
#define LOAD_SEG(BASE, STRIDE)                                                 \
    _Pragma("unroll")                                                          \
    for (int j = 0; j < 16; ++j)                                               \
        g[j] = *((const float4*)((BASE) + j * (STRIDE)) + lane);

    // Consume g: accumulate per-lane LN partials, pack to bf16, write As with
    // 16B-chunk XOR swizzle (chunk c = lane>>1, half = lane&1; c ^= row&7).
#define STATS_CVT_WRITE()                                                      \
    _Pragma("unroll")                                                          \
    for (int j = 0; j < 16; ++j) {                                             \
        float4 v = g[j];                                                       \
        s1[j] += v.x + v.y + v.z + v.w;                                        \
        s2[j] += v.x*v.x + v.y*v.y + v.z*v.z + v.w*v.w;                        \
        int m_ = r0 + j;                                                       \
        unsigned long long pk_ = (unsigned long long)f2bf_pk(v.x, v.y)         \
                               | ((unsigned long long)f2bf_pk(v.z, v.w) << 32);\
        As8[(m_ * 32 + ((lane >> 1) ^ (j & 7))) * 2 + (lane & 1)] = pk_;       \
    }

    // B loads coalesced: per (kc,nt) the wave reads a contiguous 1KB of
    // w1L[kb = SEG*8+kc][n0+nt*16 .. +16][0..32).
#define MFMA_SEG(SEG)                                                          \
    _Pragma("unroll")                                                          \
    for (int kc = 0; kc < 8; ++kc) {                                           \
        const short* wk_ = w1t + ((SEG) * 8 + kc) * 8192;                      \
        s16x8 bfr[4];                                                          \
        _Pragma("unroll")                                                      \
        for (int nt = 0; nt < 4; ++nt)                                         \
            bfr[nt] = *(const s16x8*)(wk_ + (n0 + nt * 16 + l15) * 32 + q * 8);\
        s16x8 afr[4];                                                          \
        _Pragma("unroll")                                                      \
        for (int mt = 0; mt < 4; ++mt) {                                       \
            int m_ = mt * 16 + l15;                                            \
            afr[mt] = *(const s16x8*)&As[m_ * 32 + ((kc * 4 + q) ^ (m_ & 7))]; \
        }                                                                      \
        _Pragma("unroll")                                                      \
        for (int mt = 0; mt < 4; ++mt)                                         \
            _Pragma("unroll")                                                  \
            for (int nt = 0; nt < 4; ++nt)                                     \
                acc[mt][nt] = __builtin_amdgcn_mfma_f32_16x16x32_bf16(         \
                    afr[mt], bfr[nt], acc[mt][nt], 0, 0, 0);                   \
    }

    // ---- software-pipelined GEMM1: load(s+1) issued before MFMA(s) --------
    LOAD_SEG(base0, 0);            // token broadcast (CSEs to one load)
    STATS_CVT_WRITE();
    __syncthreads();
    LOAD_SEG(base1, 256);
    MFMA_SEG(0);
    __syncthreads();
    STATS_CVT_WRITE();
    __syncthreads();
    LOAD_SEG(base2, 256);
    MFMA_SEG(1);
    __syncthreads();
    STATS_CVT_WRITE();
    __syncthreads();
    LOAD_SEG(base3, 256);
    MFMA_SEG(2);
    __syncthreads();
    STATS_CVT_WRITE();
    __syncthreads();
    LOAD_SEG(base4, 256);
    MFMA_SEG(3);
    __syncthreads();
    STATS_CVT_WRITE();
    __syncthreads();
    MFMA_SEG(4);
    __syncthreads();               // As reads done everywhere; pst may overlay

    // ---- LN stats: per-lane partials -> pst (aliases As) -> 1-wave reduce -
    // write: lane l, row r: f32 index ((l>>2)^(r&7))*4 + (l&3) within row.
#pragma unroll
    for (int j = 0; j < 16; ++j) {
        int r  = r0 + j;
        int ci = (((lane >> 2) ^ (j & 7)) << 2) + (lane & 3);
        pst[r * 64 + ci]        = s1[j];
        pst[4096 + r * 64 + ci] = s2[j];
    }
    __syncthreads();

    if (t < 64) {
        const int r = t;
        float S1 = 0.f, S2 = 0.f;
#pragma unroll
        for (int i = 0; i < 16; ++i) {
            int c = i ^ (r & 7);
            const f32x4 a = *(const f32x4*)&pst[r * 64 + (c << 2)];
            const f32x4 b = *(const f32x4*)&pst[4096 + r * 64 + (c << 2)];
            S1 += a[0] + a[1] + a[2] + a[3];
            S2 += b[0] + b[1] + b[2] + b[3];
        }
        float x0 = rel[(bm * 64 + r) * 2 + 0];
        float x1 = rel[(bm * 64 + r) * 2 + 1];
        float x2 = vis[bm * 64 + r];
        S1 += x0 + x1 + x2;
        S2 += x0 * x0 + x1 * x1 + x2 * x2;
        const float inv = 1.0f / 1283.0f;
        float mu  = S1 * inv;
        float var = S2 * inv - mu * mu;
        float rs  = rsqrtf(var + 1e-5f);
        mu_s[r] = mu;
        rs_s[r] = rs;
        t0s[r] = (x0 - mu) * rs * gamma[1280] + beta[1280];
        t1s[r] = (x1 - mu) * rs * gamma[1281] + beta[1281];
        t2s[r] = (x2 - mu) * rs * gamma[1282] + beta[1282];
    }
    __syncthreads();               // stats published; pst reads done

    // ---- epilogue 1: LN fixup + tail + bias + GELU -> y1 bf16 (overlays) --
#pragma unroll
    for (int nt = 0; nt < 4; ++nt) {
        int n = n0 + nt * 16 + l15;
        float sg  = Sg[n], sb = Sb[n], bb = b1v[n];
        float wt0 = W1[1280 * 256 + n];
        float wt1 = W1[1281 * 256 + n];
        float wt2 = W1[1282 * 256 + n];
#pragma unroll
    for (int mt = 0; mt < 4; ++mt) {
#pragma unroll
            for (int r4 = 0; r4 < 4; ++r4) {
                int r = mt * 16 + q * 4 + r4;
                float rsv = rs_s[r], muv = mu_s[r];
                float v = rsv * acc[mt][nt][r4] - rsv * muv * sg + sb + bb
                        + t0s[r] * wt0 + t1s[r] * wt1 + t2s[r] * wt2;
                v = gelu_t(v);
                int chunk = (n >> 3) ^ (r & 7);
                y16[(r * 32 + chunk) * 8 + (n & 7)] = f2bf(v);
            }
        }
    }
    __syncthreads();

    // ---- GEMM2: y1 (bf16 in LDS) @ w2L (coalesced global) -----------------
    f32x4 acc2[4][4];
#pragma unroll
    for (int i = 0; i < 4; ++i)
#pragma unroll
        for (int j = 0; j < 4; ++j)
            acc2[i][j] = (f32x4){0.f, 0.f, 0.f, 0.f};

#pragma unroll
    for (int kc = 0; kc < 8; ++kc) {
        const short* wk = w2t + kc * 8192;
        s16x8 bfr[4];
#pragma unroll
        for (int nt = 0; nt < 4; ++nt)
            bfr[nt] = *(const s16x8*)(wk + (n0 + nt * 16 + l15) * 32 + q * 8);
        s16x8 afr[4];
#pragma unroll
        for (int mt = 0; mt < 4; ++mt) {
            int m_ = mt * 16 + l15;
            afr[mt] = *(const s16x8*)&As[m_ * 32 + ((kc * 4 + q) ^ (m_ & 7))];
        }
#pragma unroll
        for (int mt = 0; mt < 4; ++mt)
#pragma unroll
            for (int nt = 0; nt < 4; ++nt)
                acc2[mt][nt] = __builtin_amdgcn_mfma_f32_16x16x32_bf16(
                    afr[mt], bfr[nt], acc2[mt][nt], 0, 0, 0);
    }

    // ---- epilogue 2: + b2, GELU, store f32 --------------------------------
#pragma unroll
    for (int nt = 0; nt < 4; ++nt) {
        int n = n0 + nt * 16 + l15;
        float bb = b2v[n];
#pragma unroll
        for (int mt = 0; mt < 4; ++mt)
#pragma unroll
            for (int r4 = 0; r4 < 4; ++r4) {
                int r = mt * 16 + q * 4 + r4;
                out[(bm * 64 + r) * 256 + n] = gelu_t(acc2[mt][nt][r4] + bb);
            }
    }
#undef LOAD_SEG
#undef STATS_CVT_WRITE
#undef MFMA_SEG
}

// ---------------------------------------------------------------------------
extern "C" void kernel_launch(void* const* d_in, const int* in_sizes, int n_in,
                              void* d_out, int out_size, void* d_ws, size_t ws_size,
                              hipStream_t stream) {
    const float* token = (const float*)d_in[0];
    const float* step  = (const float*)d_in[1];
    const float* dyn   = (const float*)d_in[2];
    const float* sem   = (const float*)d_in[3];
    const float* trace = (const float*)d_in[4];
    const float* rel   = (const float*)d_in[5];
    const float* vis   = (const float*)d_in[6];
    const float* gamma = (const float*)d_in[7];
    const float* beta  = (const float*)d_in[8];
    const float* W1    = (const float*)d_in[9];
    const float* b1    = (const float*)d_in[10];
    const float* W2    = (const float*)d_in[11];
    const float* b2    = (const float*)d_in[12];

    // ws layout: [0,1KB) Sg f32, [1KB,2KB) Sb f32, then w1L bf16 (655360 B),
    // then w2L bf16 (131072 B).  Total 788480 B.
    float* Sg  = (float*)d_ws;
    float* Sb  = Sg + 256;
    short* w1t = (short*)((char*)d_ws + 2048);
    short* w2t = w1t + 1280 * 256;
    float* out = (float*)d_out;

    hipLaunchKernelGGL(prep_k, dim3(49), dim3(256), 0, stream,
                       W1, W2, gamma, beta, Sg, Sb, w1t, w2t);
    hipLaunchKernelGGL(fused_main, dim3(1024), dim3(256), 0, stream,
                       token, step, dyn, sem, trace, rel, vis, gamma, beta,
                       W1, b1, b2, Sg, Sb, w1t, w2t, out);
}